// Round 6
// baseline (533.956 us; speedup 1.0000x reference)
//
#include <hip/hip_runtime.h>
#include <math.h>

// Problem dims (from reference): B=4, C=64, T=16, H=128, W=128, fp32.
#define BB 4
#define CC 64
#define TT 16
#define HH 128
#define WW 128
#define HW (HH*WW)
#define HALO 16           // max spatial dilation
#define PW (WW + 2*HALO)  // padded LDS row stride = 160 floats

typedef float f32x4 __attribute__((ext_vector_type(4)));

__device__ __forceinline__ float softplus_f(float x) {
    return (x > 20.0f) ? x : log1pf(expf(x));
}

// Barrier that orders LDS traffic only (s_waitcnt lgkmcnt(0)) and does NOT
// drain vmcnt — __syncthreads() would emit s_waitcnt vmcnt(0), killing the
// cross-iteration global prefetch (measured: round-4 regression 129->140us,
// fixed to 121us in round 5 by this barrier).
__device__ __forceinline__ void barrier_lgkm() {
    asm volatile("s_waitcnt lgkmcnt(0)\n\ts_barrier" ::: "memory");
}

// Two blocks per CU (each 1024 threads, 80 KB LDS -> 2x80 = 160 KB pool,
// 32 waves/CU). Block (half, bc) handles t in [8*half, 8*half+8) of plane
// stack bc. Independent blocks interleave their barrier/stage/compute
// phases -> CU always has runnable waves (round-5 kernel was 1 block/CU in
// lockstep: occupancy 41%, 4.4 TB/s).
//  - temporal history (t-1, t-2) in registers (half=1 prologue-loads planes
//    t0-1, t0-2; same-XCD sibling streams them too -> mostly L2/L3 hits)
//  - plane t+1 prefetched into registers across lgkm-only barriers
//  - spatial taps via full-plane LDS buffer with 16-col replicate halo
__global__ __launch_bounds__(1024, 8) void lap_st_kernel(
    const float* __restrict__ u,
    const float* __restrict__ Ds,   // (3, 64)
    const float* __restrict__ Dt,   // (2, 64)
    float* __restrict__ out)
{
    __shared__ __align__(16) float sm[HH * PW];

    const int bid  = blockIdx.x;
    const int half = bid >> 8;             // 0: t=0..7, 1: t=8..15
    const int bc   = bid & 255;            // b*C + c
    const int c    = bc & (CC - 1);
    const int t0   = half << 3;
    const int tid  = threadIdx.x;

    const float cs0 = softplus_f(Ds[0 * CC + c]);
    const float cs1 = softplus_f(Ds[1 * CC + c]);
    const float cs2 = softplus_f(Ds[2 * CC + c]);
    const float ct0 = softplus_f(Dt[0 * CC + c]);
    const float ct1 = softplus_f(Dt[1 * CC + c]);
    const float cu = -4.0f * (cs0 + cs1 + cs2) - (ct0 + ct1);

    const size_t bc_off = (size_t)bc * TT * HW;

    float4 nxt[4], cur[4], pm1[4], pm2[4];

    // prologue: load plane t0 into cur; history = planes t0-1, t0-2
    {
        const float4* up4 = (const float4*)(u + bc_off + (size_t)t0 * HW);
        #pragma unroll
        for (int i = 0; i < 4; ++i) cur[i] = up4[tid + (i << 10)];
        if (half == 0) {   // causal clamp: u[-1] = u[-2] = u[0]
            #pragma unroll
            for (int i = 0; i < 4; ++i) { pm1[i] = cur[i]; pm2[i] = cur[i]; }
        } else {
            const float4* q1 = (const float4*)(u + bc_off + (size_t)(t0 - 1) * HW);
            const float4* q2 = (const float4*)(u + bc_off + (size_t)(t0 - 2) * HW);
            #pragma unroll
            for (int i = 0; i < 4; ++i) { pm1[i] = q1[tid + (i << 10)]; pm2[i] = q2[tid + (i << 10)]; }
        }
    }

    for (int tt = 0; tt < 8; ++tt) {
        const int t = t0 + tt;
        f32x4* out4 = (f32x4*)(out + bc_off + (size_t)t * HW);

        barrier_lgkm();   // prev iteration's LDS reads done -> safe to overwrite sm

        // ---- prefetch plane t+1 (issue only; completes during compute) ----
        if (tt < 7) {
            const float4* up4 = (const float4*)(u + bc_off + (size_t)(t + 1) * HW);
            #pragma unroll
            for (int i = 0; i < 4; ++i) nxt[i] = up4[tid + (i << 10)];
        }

        // ---- stage plane t into LDS from registers; halos splatted inline ----
        #pragma unroll
        for (int i = 0; i < 4; ++i) {
            const int k = tid + (i << 10);       // chunk index 0..4095
            const float4 v = cur[i];
            const int row  = k >> 5;             // 32 float4-chunks per row
            const int colc = k & 31;
            *(float4*)&sm[row * PW + HALO + (colc << 2)] = v;
            if (colc == 0) {                      // left replicate halo
                float4 s = make_float4(v.x, v.x, v.x, v.x);
                float* hp = &sm[row * PW];
                *(float4*)&hp[0] = s; *(float4*)&hp[4] = s;
                *(float4*)&hp[8] = s; *(float4*)&hp[12] = s;
            } else if (colc == 31) {              // right replicate halo
                float4 s = make_float4(v.w, v.w, v.w, v.w);
                float* hp = &sm[row * PW + HALO + WW];
                *(float4*)&hp[0] = s; *(float4*)&hp[4] = s;
                *(float4*)&hp[8] = s; *(float4*)&hp[12] = s;
            }
        }

        barrier_lgkm();   // LDS writes visible; prefetch loads still in flight

        // ---- compute ----
        #pragma unroll
        for (int i = 0; i < 4; ++i) {
            const int k   = tid + (i << 10);
            const int row = k >> 5;
            const int col = (k & 31) << 2;
            const float* rp = &sm[row * PW + HALO];

            const int rU1  = (row >= 1)       ? row - 1  : 0;
            const int rD1  = (row <= HH - 2)  ? row + 1  : HH - 1;
            const int rU4  = (row >= 4)       ? row - 4  : 0;
            const int rD4  = (row <= HH - 5)  ? row + 4  : HH - 1;
            const int rU16 = (row >= 16)      ? row - 16 : 0;
            const int rD16 = (row <= HH - 17) ? row + 16 : HH - 1;

            const float4 c0   = cur[i];   // center from registers
            const float4 vu1  = *(const float4*)&sm[rU1  * PW + HALO + col];
            const float4 vd1  = *(const float4*)&sm[rD1  * PW + HALO + col];
            const float4 vu4  = *(const float4*)&sm[rU4  * PW + HALO + col];
            const float4 vd4  = *(const float4*)&sm[rD4  * PW + HALO + col];
            const float4 vu16 = *(const float4*)&sm[rU16 * PW + HALO + col];
            const float4 vd16 = *(const float4*)&sm[rD16 * PW + HALO + col];
            const float4 l4   = *(const float4*)&rp[col - 4];
            const float4 r4   = *(const float4*)&rp[col + 4];
            const float4 l16  = *(const float4*)&rp[col - 16];
            const float4 r16  = *(const float4*)&rp[col + 16];

            const float4 p1 = pm1[i];
            const float4 p2 = pm2[i];

            f32x4 o;
            o.x = cs0 * (vu1.x + vd1.x + l4.w + c0.y)
                + cs1 * (vu4.x + vd4.x + l4.x + r4.x)
                + cs2 * (vu16.x + vd16.x + l16.x + r16.x)
                + cu * c0.x + ct0 * p1.x + ct1 * p2.x;
            o.y = cs0 * (vu1.y + vd1.y + c0.x + c0.z)
                + cs1 * (vu4.y + vd4.y + l4.y + r4.y)
                + cs2 * (vu16.y + vd16.y + l16.y + r16.y)
                + cu * c0.y + ct0 * p1.y + ct1 * p2.y;
            o.z = cs0 * (vu1.z + vd1.z + c0.y + c0.w)
                + cs1 * (vu4.z + vd4.z + l4.z + r4.z)
                + cs2 * (vu16.z + vd16.z + l16.z + r16.z)
                + cu * c0.z + ct0 * p1.z + ct1 * p2.z;
            o.w = cs0 * (vu1.w + vd1.w + c0.z + r4.x)
                + cs1 * (vu4.w + vd4.w + l4.w + r4.w)
                + cs2 * (vu16.w + vd16.w + l16.w + r16.w)
                + cu * c0.w + ct0 * p1.w + ct1 * p2.w;

            __builtin_nontemporal_store(o, &out4[k]);   // streaming output, never re-read
        }

        // rotate temporal history; cur <- nxt is where the vmcnt wait lands
        if (tt < 7) {
            #pragma unroll
            for (int i = 0; i < 4; ++i) { pm2[i] = pm1[i]; pm1[i] = cur[i]; cur[i] = nxt[i]; }
        }
    }
}

extern "C" void kernel_launch(void* const* d_in, const int* in_sizes, int n_in,
                              void* d_out, int out_size, void* d_ws, size_t ws_size,
                              hipStream_t stream) {
    const float* u  = (const float*)d_in[0];
    const float* Ds = (const float*)d_in[1];
    const float* Dt = (const float*)d_in[2];
    float* out = (float*)d_out;

    const int nblocks = 2 * BB * CC;   // 512 -> two independent blocks per CU
    lap_st_kernel<<<dim3(nblocks), dim3(1024), 0, stream>>>(u, Ds, Dt, out);
}

// Round 7
// 121.917 us; speedup vs baseline: 4.3797x; 4.3797x over previous
//
#include <hip/hip_runtime.h>
#include <math.h>

// Problem dims (from reference): B=4, C=64, T=16, H=128, W=128, fp32.
#define BB 4
#define CC 64
#define TT 16
#define HH 128
#define WW 128
#define HW (HH*WW)
#define HALO 16           // max spatial dilation
#define PW (WW + 2*HALO)  // padded LDS row stride = 160 floats

typedef float f32x4 __attribute__((ext_vector_type(4)));

__device__ __forceinline__ float softplus_f(float x) {
    return (x > 20.0f) ? x : log1pf(expf(x));
}

// Barrier that orders LDS traffic only (s_waitcnt lgkmcnt(0)) and does NOT
// drain vmcnt — __syncthreads() would emit s_waitcnt vmcnt(0), killing the
// cross-iteration global prefetch (measured: 140us with __syncthreads,
// 121us with this barrier).
__device__ __forceinline__ void barrier_lgkm() {
    asm volatile("s_waitcnt lgkmcnt(0)\n\ts_barrier" ::: "memory");
}

// 512 blocks of 1024 threads: block (half, bc) handles t in [8*half, 8*half+8)
// of plane stack bc. 80 KB LDS/block -> two blocks co-resident per CU
// (2x80 = 160 KB pool), so the two blocks' barrier/stage/compute phases
// interleave and the HBM pipes stay fed.
//
// __launch_bounds__(1024, 4): round-6 used (1024, 8) -> compiler capped at
// 32 VGPR -> 64-float live state spilled to scratch -> FETCH 1 GB, 534us.
// (1024, 4) measurably compiles this body to 64 VGPR (round 5), and
// 64 VGPR x 8 waves/SIMD = 512 = full pool, so 2-block residency still fits.
//  - temporal history (t-1, t-2) in registers
//  - plane t+1 prefetched into registers across lgkm-only barriers
//  - spatial taps via full-plane LDS buffer with 16-col replicate halo
__global__ __launch_bounds__(1024, 4) void lap_st_kernel(
    const float* __restrict__ u,
    const float* __restrict__ Ds,   // (3, 64)
    const float* __restrict__ Dt,   // (2, 64)
    float* __restrict__ out)
{
    __shared__ __align__(16) float sm[HH * PW];

    const int bid  = blockIdx.x;
    const int half = bid >> 8;             // 0: t=0..7, 1: t=8..15
    const int bc   = bid & 255;            // b*C + c
    const int c    = bc & (CC - 1);
    const int t0   = half << 3;
    const int tid  = threadIdx.x;

    const float cs0 = softplus_f(Ds[0 * CC + c]);
    const float cs1 = softplus_f(Ds[1 * CC + c]);
    const float cs2 = softplus_f(Ds[2 * CC + c]);
    const float ct0 = softplus_f(Dt[0 * CC + c]);
    const float ct1 = softplus_f(Dt[1 * CC + c]);
    const float cu = -4.0f * (cs0 + cs1 + cs2) - (ct0 + ct1);

    const size_t bc_off = (size_t)bc * TT * HW;

    float4 nxt[4], cur[4], pm1[4], pm2[4];

    // prologue: load plane t0 into cur; history = planes t0-1, t0-2
    {
        const float4* up4 = (const float4*)(u + bc_off + (size_t)t0 * HW);
        #pragma unroll
        for (int i = 0; i < 4; ++i) cur[i] = up4[tid + (i << 10)];
        if (half == 0) {   // causal clamp: u[-1] = u[-2] = u[0]
            #pragma unroll
            for (int i = 0; i < 4; ++i) { pm1[i] = cur[i]; pm2[i] = cur[i]; }
        } else {
            const float4* q1 = (const float4*)(u + bc_off + (size_t)(t0 - 1) * HW);
            const float4* q2 = (const float4*)(u + bc_off + (size_t)(t0 - 2) * HW);
            #pragma unroll
            for (int i = 0; i < 4; ++i) { pm1[i] = q1[tid + (i << 10)]; pm2[i] = q2[tid + (i << 10)]; }
        }
    }

    for (int tt = 0; tt < 8; ++tt) {
        const int t = t0 + tt;
        f32x4* out4 = (f32x4*)(out + bc_off + (size_t)t * HW);

        barrier_lgkm();   // prev iteration's LDS reads done -> safe to overwrite sm

        // ---- prefetch plane t+1 (issue only; completes during compute) ----
        if (tt < 7) {
            const float4* up4 = (const float4*)(u + bc_off + (size_t)(t + 1) * HW);
            #pragma unroll
            for (int i = 0; i < 4; ++i) nxt[i] = up4[tid + (i << 10)];
        }

        // ---- stage plane t into LDS from registers; halos splatted inline ----
        #pragma unroll
        for (int i = 0; i < 4; ++i) {
            const int k = tid + (i << 10);       // chunk index 0..4095
            const float4 v = cur[i];
            const int row  = k >> 5;             // 32 float4-chunks per row
            const int colc = k & 31;
            *(float4*)&sm[row * PW + HALO + (colc << 2)] = v;
            if (colc == 0) {                      // left replicate halo
                float4 s = make_float4(v.x, v.x, v.x, v.x);
                float* hp = &sm[row * PW];
                *(float4*)&hp[0] = s; *(float4*)&hp[4] = s;
                *(float4*)&hp[8] = s; *(float4*)&hp[12] = s;
            } else if (colc == 31) {              // right replicate halo
                float4 s = make_float4(v.w, v.w, v.w, v.w);
                float* hp = &sm[row * PW + HALO + WW];
                *(float4*)&hp[0] = s; *(float4*)&hp[4] = s;
                *(float4*)&hp[8] = s; *(float4*)&hp[12] = s;
            }
        }

        barrier_lgkm();   // LDS writes visible; prefetch loads still in flight

        // ---- compute ----
        #pragma unroll
        for (int i = 0; i < 4; ++i) {
            const int k   = tid + (i << 10);
            const int row = k >> 5;
            const int col = (k & 31) << 2;
            const float* rp = &sm[row * PW + HALO];

            const int rU1  = (row >= 1)       ? row - 1  : 0;
            const int rD1  = (row <= HH - 2)  ? row + 1  : HH - 1;
            const int rU4  = (row >= 4)       ? row - 4  : 0;
            const int rD4  = (row <= HH - 5)  ? row + 4  : HH - 1;
            const int rU16 = (row >= 16)      ? row - 16 : 0;
            const int rD16 = (row <= HH - 17) ? row + 16 : HH - 1;

            const float4 c0   = cur[i];   // center from registers
            const float4 vu1  = *(const float4*)&sm[rU1  * PW + HALO + col];
            const float4 vd1  = *(const float4*)&sm[rD1  * PW + HALO + col];
            const float4 vu4  = *(const float4*)&sm[rU4  * PW + HALO + col];
            const float4 vd4  = *(const float4*)&sm[rD4  * PW + HALO + col];
            const float4 vu16 = *(const float4*)&sm[rU16 * PW + HALO + col];
            const float4 vd16 = *(const float4*)&sm[rD16 * PW + HALO + col];
            const float4 l4   = *(const float4*)&rp[col - 4];
            const float4 r4   = *(const float4*)&rp[col + 4];
            const float4 l16  = *(const float4*)&rp[col - 16];
            const float4 r16  = *(const float4*)&rp[col + 16];

            const float4 p1 = pm1[i];
            const float4 p2 = pm2[i];

            f32x4 o;
            o.x = cs0 * (vu1.x + vd1.x + l4.w + c0.y)
                + cs1 * (vu4.x + vd4.x + l4.x + r4.x)
                + cs2 * (vu16.x + vd16.x + l16.x + r16.x)
                + cu * c0.x + ct0 * p1.x + ct1 * p2.x;
            o.y = cs0 * (vu1.y + vd1.y + c0.x + c0.z)
                + cs1 * (vu4.y + vd4.y + l4.y + r4.y)
                + cs2 * (vu16.y + vd16.y + l16.y + r16.y)
                + cu * c0.y + ct0 * p1.y + ct1 * p2.y;
            o.z = cs0 * (vu1.z + vd1.z + c0.y + c0.w)
                + cs1 * (vu4.z + vd4.z + l4.z + r4.z)
                + cs2 * (vu16.z + vd16.z + l16.z + r16.z)
                + cu * c0.z + ct0 * p1.z + ct1 * p2.z;
            o.w = cs0 * (vu1.w + vd1.w + c0.z + r4.x)
                + cs1 * (vu4.w + vd4.w + l4.w + r4.w)
                + cs2 * (vu16.w + vd16.w + l16.w + r16.w)
                + cu * c0.w + ct0 * p1.w + ct1 * p2.w;

            __builtin_nontemporal_store(o, &out4[k]);   // streaming output, never re-read
        }

        // rotate temporal history; cur <- nxt is where the vmcnt wait lands
        if (tt < 7) {
            #pragma unroll
            for (int i = 0; i < 4; ++i) { pm2[i] = pm1[i]; pm1[i] = cur[i]; cur[i] = nxt[i]; }
        }
    }
}

extern "C" void kernel_launch(void* const* d_in, const int* in_sizes, int n_in,
                              void* d_out, int out_size, void* d_ws, size_t ws_size,
                              hipStream_t stream) {
    const float* u  = (const float*)d_in[0];
    const float* Ds = (const float*)d_in[1];
    const float* Dt = (const float*)d_in[2];
    float* out = (float*)d_out;

    const int nblocks = 2 * BB * CC;   // 512 -> two independent blocks per CU
    lap_st_kernel<<<dim3(nblocks), dim3(1024), 0, stream>>>(u, Ds, Dt, out);
}